// Round 18
// baseline (127.220 us; speedup 1.0000x reference)
//
#include <hip/hip_runtime.h>

#define TT   256        // output positions per side per block
#define TIN2 (TT + 8)   // staged X: pos -4 .. TT+3
#define NHA  (TT + 6)   // hid rows: pos -3 .. TT+2
#define NEO  (TT + 4)   // Es/Os rows: pos -2 .. TT+1
#define NHB  (TT + 2)   // hidB rows: pos -1 .. TT

typedef _Float16 h2 __attribute__((ext_vector_type(2)));
typedef __fp16 fp16v2 __attribute__((ext_vector_type(2)));
typedef _Float16 f16x8 __attribute__((ext_vector_type(8)));
typedef float f32x4 __attribute__((ext_vector_type(4)));

// MFMA A-fragments of conv weights (device-global; rewritten every launch).
__device__ _Float16 g_w1A[12][2][64][8];  // conv1: [lvl*4+pair][Mtile][lane][j], k=kk*8+ic (kk=3 zero)
__device__ _Float16 g_w2A[12][3][64][8];  // conv2: [lvl*4+pair][tap][lane][j], hc PERMUTED (see pack), oc rows 8..15 zero

__device__ __forceinline__ h2 pkh(float a, float b) {
  fp16v2 r = __builtin_amdgcn_cvt_pkrtz(a, b);
  return __builtin_bit_cast(h2, r);
}
__device__ __forceinline__ unsigned int pku(float a, float b) {
  return __builtin_bit_cast(unsigned int, pkh(a, b));
}
__device__ __forceinline__ float fast_tanh(float x) {
  return 1.f - __fdividef(2.f, __expf(2.f * x) + 1.f);
}
// packed leaky: max(x, 0.01x) elementwise on 2 halves (v_pk_mul + v_pk_max)
__device__ __forceinline__ unsigned int lky(unsigned int u) {
  h2 v = __builtin_bit_cast(h2, u);
  h2 s = v * (h2){(_Float16)0.01f, (_Float16)0.01f};
  h2 m = __builtin_elementwise_max(v, s);
  return __builtin_bit_cast(unsigned int, m);
}
// lanes 0-31 keep a; lanes 32-63 receive b from (lane-32). Known-good
// __shfl_xor form (v_permlane32_swap failed in both operand orders, R15/R16).
__device__ __forceinline__ float lane_spread(float a_low, float b_low, int lane) {
  float s = __shfl_xor(b_low, 32);
  return (lane >= 32) ? s : a_low;
}
// swizzled 16B-group slot within a 64B hid row (bijective per row, same on R/W)
#define HID_PTR(row, g) (&hidS[row][(((g) ^ (((row) >> 1) & 3)) * 8)])

__global__ __launch_bounds__(256) void pack_mfma(
    const float* __restrict__ w1, const float* __restrict__ w2)
{
  int id = blockIdx.x * 256 + threadIdx.x;
  if (id >= 12 * 5 * 64) return;
  const int lane = id & 63;
  const int rest = id >> 6;
  const int slot = rest % 5;
  const int pr   = rest / 5;           // lvl*4+pair
  if (slot < 2) {                      // conv1 A-fragment, M-tile = slot
    const int oc = slot * 16 + (lane & 15);
    const int bb = lane >> 4;          // tap index; bb=3 -> zero pad
#pragma unroll
    for (int j = 0; j < 8; ++j) {
      float v = (bb < 3) ? w1[((size_t)pr * 32 + oc) * 24 + j * 3 + bb] : 0.f;
      g_w1A[pr][slot][lane][j] = (_Float16)v;
    }
  } else {                             // conv2 A-fragment, tap t; hc permuted to match
    const int t = slot - 2;            // hid LDS layout: offset 8*kk+j -> hc below
    const int oc = lane & 15;
    const int kk = lane >> 4;
#pragma unroll
    for (int j = 0; j < 8; ++j) {
      const int hc = (j < 4) ? (4 * kk + j) : (16 + 4 * kk + (j - 4));
      float v = (oc < 8) ? w2[((size_t)pr * 8 + oc) * 96 + hc * 3 + t] : 0.f;
      g_w2A[pr][t][lane][j] = (_Float16)v;
    }
  }
}

// Fused level, 512 threads = 8 waves; sides processed SEQUENTIALLY so a single
// hid plane suffices (LDS 49->33 KB => 4 blocks/CU = 32 waves, the occupancy
// cap). Wave w owns tiles {2w,2w+1} (+tile16 for w7 in A2); its 1-phase span
// is tiles 2w..2w+2 (+1 halo, identical-byte overlaps, R17-proven). Cross-side
// hid overwrites are barrier-fenced (4 barriers total).
template <bool IN16>
__global__ __launch_bounds__(512, 8) void level_fused(
    const void* __restrict__ Xv, _Float16* __restrict__ NEXT,
    int lvl, int T2, int tilesPerSeq)
{
  __shared__ __align__(16) _Float16 inS[2][TIN2][8];    // [side][pos+4][ch]
  __shared__ __align__(16) _Float16 hidS[NHA][32];      // single side, swizzled
  __shared__ __align__(16) _Float16 esS[2][NEO][8];     // Es/Os f16 (B conv input + base)

  const int blk = blockIdx.x;
  const int nb  = blk / tilesPerSeq;
  const int t0  = (blk - nb * tilesPerSeq) * TT;

  if constexpr (IN16) {
    // pos-major f16: row (2p+s) of 8 f16 = 16B -> one uint4 per (side,pos)
    const _Float16* Xh = (const _Float16*)Xv + (size_t)nb * (2 * (size_t)T2) * 8;
    for (int it = threadIdx.x; it < 2 * TIN2; it += 512) {
      const int s = it & 1, jj = it >> 1;
      int p = t0 - 4 + jj;
      p = p < 0 ? 0 : (p > T2 - 1 ? T2 - 1 : p);     // clamp in side-position space
      *(uint4*)&inS[s][jj][0] = *(const uint4*)&Xh[(size_t)(2 * p + s) * 8];
    }
  } else {
    const float* X = (const float*)Xv;
    const float2* Xrow = (const float2*)(X + (size_t)nb * 8 * (2 * (size_t)T2));
    for (int jj = threadIdx.x; jj < TIN2; jj += 512) {
      int j = t0 - 4 + jj;
      j = j < 0 ? 0 : (j > T2 - 1 ? T2 - 1 : j);
      unsigned int u0[4], u1[4];
#pragma unroll
      for (int cp = 0; cp < 4; ++cp) {
        float2 a = Xrow[(size_t)(2 * cp) * T2 + j];
        float2 b = Xrow[(size_t)(2 * cp + 1) * T2 + j];
        u0[cp] = pku(a.x, b.x);                      // side0 = odd
        u1[cp] = pku(a.y, b.y);                      // side1 = even
      }
      *(uint4*)&inS[0][jj][0] = make_uint4(u0[0], u0[1], u0[2], u0[3]);
      *(uint4*)&inS[1][jj][0] = make_uint4(u1[0], u1[1], u1[2], u1[3]);
    }
  }
  __syncthreads();

  const int wid  = __builtin_amdgcn_readfirstlane((int)(threadIdx.x >> 6));  // 0..7
  const int lane = threadIdx.x & 63;
  const int g = lane >> 4, col = lane & 15;
  const int t2 = 2 * wid;                               // first owned tile
  const int a2cnt = (wid == 7) ? 3 : 2;                 // w7 also covers tile 16
  const int rp = ((lane >> 4) & 1) * 2 + (lane >> 5);   // row-pair after lane_spread

  const f32x4 zero = {0.f, 0.f, 0.f, 0.f};
  const int i = nb >> 7;          // B = 128
  const int b = nb & 127;

  // ================= A phases (per side) =================
#pragma unroll
  for (int s = 0; s < 2; ++s) {
    const int pa = lvl * 4 + (s ? 3 : 1);
    const f16x8 a1w0 = *(const f16x8*)&g_w1A[pa][0][lane][0];
    const f16x8 a1w1 = *(const f16x8*)&g_w1A[pa][1][lane][0];
    const f16x8 a2w0 = *(const f16x8*)&g_w2A[pa][0][lane][0];
    const f16x8 a2w1 = *(const f16x8*)&g_w2A[pa][1][lane][0];
    const f16x8 a2w2 = *(const f16x8*)&g_w2A[pa][2][lane][0];

    // A1: tiles t2..t2+2 (own span + halo); swizzled b128 writes
#pragma unroll
    for (int nt = 0; nt < 3; ++nt) {
      const int row = (t2 + nt) * 16 + col;
      const int rr = (row + g > TIN2 - 1) ? (TIN2 - 1) : (row + g);
      const f16x8 bf = *(const f16x8*)&inS[s][rr][0];
      f32x4 d0 = __builtin_amdgcn_mfma_f32_16x16x32_f16(a1w0, bf, zero, 0, 0, 0);
      f32x4 d1 = __builtin_amdgcn_mfma_f32_16x16x32_f16(a1w1, bf, zero, 0, 0, 0);
      if (row < NHA) {
        *(uint4*)HID_PTR(row, g) = make_uint4(
            lky(pku(d0[0], d0[1])), lky(pku(d0[2], d0[3])),
            lky(pku(d1[0], d1[1])), lky(pku(d1[2], d1[3])));
      }
    }
    // no barrier: A2 reads only rows this wave wrote (DS in-order within wave)

    // A2: tiles t2..t2+a2cnt-1 -> esS[s]
#pragma unroll
    for (int nt = 0; nt < 3; ++nt) {
      if (nt >= a2cnt) break;
      const int row = (t2 + nt) * 16 + col;
      f32x4 acc = zero;
      acc = __builtin_amdgcn_mfma_f32_16x16x32_f16(a2w0, *(const f16x8*)HID_PTR(row,     g), acc, 0, 0, 0);
      acc = __builtin_amdgcn_mfma_f32_16x16x32_f16(a2w1, *(const f16x8*)HID_PTR(row + 1, g), acc, 0, 0, 0);
      acc = __builtin_amdgcn_mfma_f32_16x16x32_f16(a2w2, *(const f16x8*)HID_PTR(row + 2, g), acc, 0, 0, 0);
      if (row < NEO) {
        const float va = lane_spread(acc[0], acc[2], lane);
        const float vb = lane_spread(acc[1], acc[3], lane);
        const h2 mpk = *(const h2*)&inS[s ^ 1][row + 2][2 * rp];  // multiplier (f16, staged)
        const float v0 = (float)mpk[0] * __expf(fast_tanh(va));
        const float v1 = (float)mpk[1] * __expf(fast_tanh(vb));
        *(unsigned int*)&esS[s][row][2 * rp] = pku(v0, v1);
      }
    }
    __syncthreads();   // A2(s) reads done before A1(s^1) overwrites hid;
                       // after s=1 this also fences esS for the B phases
  }

  // ================= B phases (per output side) =================
  const int eoLo = (t0 == 0) ? 2 : 0;                       // replicate-edge padding of Os/Es
  const int eoHi = (t0 + TT >= T2) ? (TT + 1) : (NEO - 1);
#pragma unroll
  for (int s = 0; s < 2; ++s) {
    const int pb = lvl * 4 + (s ? 2 : 0);
    const f16x8 b1w0 = *(const f16x8*)&g_w1A[pb][0][lane][0];
    const f16x8 b1w1 = *(const f16x8*)&g_w1A[pb][1][lane][0];
    const f16x8 b2w0 = *(const f16x8*)&g_w2A[pb][0][lane][0];
    const f16x8 b2w1 = *(const f16x8*)&g_w2A[pb][1][lane][0];
    const f16x8 b2w2 = *(const f16x8*)&g_w2A[pb][2][lane][0];
    const int srcB = s ^ 1;

    // B1: tiles t2..t2+2, conv input = other side's Es/Os
#pragma unroll
    for (int nt = 0; nt < 3; ++nt) {
      const int row = (t2 + nt) * 16 + col;
      int rr = row + g;
      rr = rr < eoLo ? eoLo : (rr > eoHi ? eoHi : rr);
      const f16x8 bf = *(const f16x8*)&esS[srcB][rr][0];
      f32x4 d0 = __builtin_amdgcn_mfma_f32_16x16x32_f16(b1w0, bf, zero, 0, 0, 0);
      f32x4 d1 = __builtin_amdgcn_mfma_f32_16x16x32_f16(b1w1, bf, zero, 0, 0, 0);
      if (row < NHB) {
        *(uint4*)HID_PTR(row, g) = make_uint4(
            lky(pku(d0[0], d0[1])), lky(pku(d0[2], d0[3])),
            lky(pku(d1[0], d1[1])), lky(pku(d1[2], d1[3])));
      }
    }
    // no barrier: B2 reads only rows this wave wrote

    // B2: tiles t2, t2+1 -> global (f16 pos-major), coalesced 4B stores
    const int outseq = 2 * i + s;
    const float sgn = s ? 1.f : -1.f;
    _Float16* outbase = NEXT + ((size_t)outseq * 128 + b) * (size_t)T2 * 8;
#pragma unroll
    for (int nt = 0; nt < 2; ++nt) {
      const int row = (t2 + nt) * 16 + col;         // output pos, exact [0,256)
      f32x4 acc = zero;
      acc = __builtin_amdgcn_mfma_f32_16x16x32_f16(b2w0, *(const f16x8*)HID_PTR(row,     g), acc, 0, 0, 0);
      acc = __builtin_amdgcn_mfma_f32_16x16x32_f16(b2w1, *(const f16x8*)HID_PTR(row + 1, g), acc, 0, 0, 0);
      acc = __builtin_amdgcn_mfma_f32_16x16x32_f16(b2w2, *(const f16x8*)HID_PTR(row + 2, g), acc, 0, 0, 0);
      const float va = lane_spread(acc[0], acc[2], lane);
      const float vb = lane_spread(acc[1], acc[3], lane);
      const h2 base = *(const h2*)&esS[srcB][row + 2][2 * rp];
      const int tg = t0 + row;
      *(unsigned int*)&outbase[(size_t)tg * 8 + 2 * rp] =
          pku((float)base[0] + sgn * fast_tanh(va), (float)base[1] + sgn * fast_tanh(vb));
    }
    if (s == 0) __syncthreads();   // B2(s0) reads done before B1(s1) overwrites hid
  }
}

// FC1 split-K (dot2, f16 operands): F[row][8t+r] = P[rev3(r)][b][t][c] + x[row][8t+r]
// P is f16 pos-major: [seq8*128+b][t(1024)][c(8)]
__global__ __launch_bounds__(256) void fc1_fused(
    const _Float16* __restrict__ P, const float* __restrict__ x,
    const float* __restrict__ W, float* __restrict__ partial)
{
  const int rt = blockIdx.x & 31;   // row tile: 32 rows
  const int ch = blockIdx.x >> 5;   // 16 chunks of 512 s
  const int s0 = ch * 512;
  __shared__ unsigned int Fl[32][68];   // h2 pairs: 64 h2 = 128 s per sub-block
  __shared__ unsigned int Wl[64][68];
  const int hg = threadIdx.x & 15;
  const int rg = threadIdx.x >> 4;  // 0..15
  float acc[2][4] = {{0.f, 0.f, 0.f, 0.f}, {0.f, 0.f, 0.f, 0.f}};

  for (int sb = 0; sb < 512; sb += 128) {
    __syncthreads();
    for (int i = threadIdx.x; i < 32 * 32; i += 256) {
      const int r = i >> 5, s4 = i & 31;
      const int row = rt * 32 + r;
      const int b = row >> 3, c = row & 7;
      const int base = s0 + sb + 4 * s4;
      const int t = base >> 3, r0 = base & 7;       // r0 in {0,4}
      const float4 xv = *(const float4*)(x + (size_t)row * 8192 + base);
      _Float16 p[4];
#pragma unroll
      for (int j = 0; j < 4; ++j) {
        const int rr = r0 + j;
        const int rev = ((rr & 1) << 2) | (rr & 2) | ((rr >> 2) & 1);   // bitrev3
        p[j] = P[(((size_t)rev * 128 + b) * 1024 + t) * 8 + c];
      }
      const h2 f01 = pkh(xv.x, xv.y) + (h2){p[0], p[1]};
      const h2 f23 = pkh(xv.z, xv.w) + (h2){p[2], p[3]};
      *(uint2*)&Fl[r][s4 * 2] = make_uint2(__builtin_bit_cast(unsigned int, f01),
                                           __builtin_bit_cast(unsigned int, f23));
    }
    for (int i = threadIdx.x; i < 64 * 32; i += 256) {
      const int hh = i >> 5, s4 = i & 31;
      float4 v = make_float4(0.f, 0.f, 0.f, 0.f);
      if (hh < 50) v = ((const float4*)(W + (size_t)hh * 8192 + s0 + sb))[s4];
      *(uint2*)&Wl[hh][s4 * 2] = make_uint2(pku(v.x, v.y), pku(v.z, v.w));
    }
    __syncthreads();
    for (int q = 0; q < 16; ++q) {
      const uint4 fa = *(const uint4*)&Fl[rg * 2][q * 4];
      const uint4 fb = *(const uint4*)&Fl[rg * 2 + 1][q * 4];
#pragma unroll
      for (int j = 0; j < 4; ++j) {
        const uint4 w = *(const uint4*)&Wl[hg + 16 * j][q * 4];
#pragma unroll
        for (int e = 0; e < 4; ++e) {
          const h2 we = __builtin_bit_cast(h2, (&w.x)[e]);
          acc[0][j] = __builtin_amdgcn_fdot2(we, __builtin_bit_cast(h2, (&fa.x)[e]), acc[0][j], false);
          acc[1][j] = __builtin_amdgcn_fdot2(we, __builtin_bit_cast(h2, (&fb.x)[e]), acc[1][j], false);
        }
      }
    }
  }
#pragma unroll
  for (int rr = 0; rr < 2; ++rr)
#pragma unroll
    for (int j = 0; j < 4; ++j)
      partial[((size_t)ch * 1024 + rt * 32 + rg * 2 + rr) * 64 + hg + 16 * j] = acc[rr][j];
}

// reduce partials + bias + relu, then FC2 -> out[row][24]; 4 rows per block
__global__ __launch_bounds__(256) void fc_stage2(
    const float* __restrict__ partial, const float* __restrict__ fc1b,
    const float* __restrict__ fc2w, const float* __restrict__ fc2b,
    float* __restrict__ out)
{
  const int rr = threadIdx.x >> 6;            // row within block: 0..3
  const int row = blockIdx.x * 4 + rr;
  const int h = threadIdx.x & 63;             // 0..63
  __shared__ float hs[4][64];
  float v = 0.f;
  if (h < 50) {
    for (int ch = 0; ch < 16; ++ch)
      v += partial[((size_t)ch * 1024 + row) * 64 + h];
    v += fc1b[h];
    v = v > 0.f ? v : 0.f;
  }
  hs[rr][h] = v;
  __syncthreads();
  if (h < 24) {
    float a = fc2b[h];
    for (int j = 0; j < 50; ++j)
      a = fmaf(hs[rr][j], fc2w[h * 50 + j], a);
    out[(size_t)row * 24 + h] = a;
  }
}

extern "C" void kernel_launch(void* const* d_in, const int* in_sizes, int n_in,
                              void* d_out, int out_size, void* d_ws, size_t ws_size,
                              hipStream_t stream)
{
  const float* x    = (const float*)d_in[0];
  const float* w1a  = (const float*)d_in[1];  // (3,4,32,8,3)
  const float* w2a  = (const float*)d_in[2];  // (3,4,8,32,3)
  const float* fc1w = (const float*)d_in[3];  // (50,8192)
  const float* fc1b = (const float*)d_in[4];  // (50,)
  const float* fc2w = (const float*)d_in[5];  // (24,50)
  const float* fc2b = (const float*)d_in[6];  // (24,)
  float* out = (float*)d_out;

  _Float16* bufA = (_Float16*)d_ws;                       // 8.4M halves (16.8 MB)
  _Float16* bufB = bufA + (size_t)9 * 1024 * 1024;        // 8.4M halves
  float* partial = (float*)((char*)d_ws + (size_t)40 * 1024 * 1024);  // 4 MB

  pack_mfma<<<dim3(15), dim3(256), 0, stream>>>(w1a, w2a);

  // lvl0: x(f32 ch-major) -> bufA(f16 pos-major) ; lvl1: bufA -> bufB ; lvl2: bufB -> bufA
  level_fused<false><<<dim3(2048), dim3(512), 0, stream>>>(x,    bufA, 0, 4096, 16);
  level_fused<true ><<<dim3(2048), dim3(512), 0, stream>>>(bufA, bufB, 1, 2048, 8);
  level_fused<true ><<<dim3(2048), dim3(512), 0, stream>>>(bufB, bufA, 2, 1024, 4);

  fc1_fused<<<dim3(512), dim3(256), 0, stream>>>(bufA, x, fc1w, partial);
  fc_stage2<<<dim3(256), dim3(256), 0, stream>>>(partial, fc1b, fc2w, fc2b, out);
  (void)in_sizes; (void)n_in; (void)out_size; (void)ws_size;
}

// Round 19
// 118.873 us; speedup vs baseline: 1.0702x; 1.0702x over previous
//
#include <hip/hip_runtime.h>

#define TT   256        // output positions per side per block
#define TIN2 (TT + 8)   // staged X: pos -4 .. TT+3
#define NHA  (TT + 6)   // hidA rows: pos -3 .. TT+2
#define NEO  (TT + 4)   // Es/Os rows: pos -2 .. TT+1
#define NHB  (TT + 2)   // hidB rows: pos -1 .. TT

typedef _Float16 h2 __attribute__((ext_vector_type(2)));
typedef __fp16 fp16v2 __attribute__((ext_vector_type(2)));
typedef _Float16 f16x8 __attribute__((ext_vector_type(8)));
typedef float f32x4 __attribute__((ext_vector_type(4)));

// MFMA A-fragments of conv weights (device-global; rewritten every launch).
__device__ _Float16 g_w1A[12][2][64][8];  // conv1: [lvl*4+pair][Mtile][lane][j], k=kk*8+ic (kk=3 zero)
__device__ _Float16 g_w2A[12][3][64][8];  // conv2: [lvl*4+pair][tap][lane][j], hc PERMUTED (see pack), oc rows 8..15 zero

__device__ __forceinline__ h2 pkh(float a, float b) {
  fp16v2 r = __builtin_amdgcn_cvt_pkrtz(a, b);
  return __builtin_bit_cast(h2, r);
}
__device__ __forceinline__ unsigned int pku(float a, float b) {
  return __builtin_bit_cast(unsigned int, pkh(a, b));
}
__device__ __forceinline__ float fast_tanh(float x) {
  return 1.f - __fdividef(2.f, __expf(2.f * x) + 1.f);
}
// packed leaky: max(x, 0.01x) elementwise on 2 halves (v_pk_mul + v_pk_max)
__device__ __forceinline__ unsigned int lky(unsigned int u) {
  h2 v = __builtin_bit_cast(h2, u);
  h2 s = v * (h2){(_Float16)0.01f, (_Float16)0.01f};
  h2 m = __builtin_elementwise_max(v, s);
  return __builtin_bit_cast(unsigned int, m);
}
// lanes 0-31 keep a; lanes 32-63 receive b from (lane-32). Known-good
// __shfl_xor form (v_permlane32_swap failed in both operand orders, R15/R16).
__device__ __forceinline__ float lane_spread(float a_low, float b_low, int lane) {
  float s = __shfl_xor(b_low, 32);
  return (lane >= 32) ? s : a_low;
}
// swizzled 16B-group slot within a 64B hid row (bijective per row, same on R/W)
#define HID_PTR(hid, side, row, g) (&(hid)[side][row][(((g) ^ (((row) >> 1) & 3)) * 8)])

__global__ __launch_bounds__(256) void pack_mfma(
    const float* __restrict__ w1, const float* __restrict__ w2)
{
  int id = blockIdx.x * 256 + threadIdx.x;
  if (id >= 12 * 5 * 64) return;
  const int lane = id & 63;
  const int rest = id >> 6;
  const int slot = rest % 5;
  const int pr   = rest / 5;           // lvl*4+pair
  if (slot < 2) {                      // conv1 A-fragment, M-tile = slot
    const int oc = slot * 16 + (lane & 15);
    const int bb = lane >> 4;          // tap index; bb=3 -> zero pad
#pragma unroll
    for (int j = 0; j < 8; ++j) {
      float v = (bb < 3) ? w1[((size_t)pr * 32 + oc) * 24 + j * 3 + bb] : 0.f;
      g_w1A[pr][slot][lane][j] = (_Float16)v;
    }
  } else {                             // conv2 A-fragment, tap t; hc permuted to match
    const int t = slot - 2;            // hid LDS layout: offset 8*kk+j -> hc below
    const int oc = lane & 15;
    const int kk = lane >> 4;
#pragma unroll
    for (int j = 0; j < 8; ++j) {
      const int hc = (j < 4) ? (4 * kk + j) : (16 + 4 * kk + (j - 4));
      float v = (oc < 8) ? w2[((size_t)pr * 8 + oc) * 96 + hc * 3 + t] : 0.f;
      g_w2A[pr][t][lane][j] = (_Float16)v;
    }
  }
}

// Fused level, 512 threads = 8 waves = 2 sides x 4 quarters (R14 structure,
// best measured). IN16 levels skip inS staging entirely: A1's B-fragment is a
// direct per-lane clamped 16B global load (input is pos-major f16, L2-hot),
// and A2's multiplier is a direct 4B global load. lvl0 (f32 ch-major) keeps
// LDS staging for the transpose.
template <bool IN16>
__global__ __launch_bounds__(512) void level_fused(
    const void* __restrict__ Xv, _Float16* __restrict__ NEXT,
    int lvl, int T2, int tilesPerSeq)
{
  constexpr int INROWS = IN16 ? 1 : TIN2;               // inS unused when IN16
  __shared__ __align__(16) _Float16 inS[2][INROWS][8];  // [side][pos+4][ch]
  __shared__ __align__(16) _Float16 hidS[2][NHA][32];   // 64B rows, swizzled 16B groups
  __shared__ __align__(16) _Float16 esS[2][NEO][8];     // Es/Os f16 (B conv input + base)

  const int blk = blockIdx.x;
  const int nb  = blk / tilesPerSeq;
  const int t0  = (blk - nb * tilesPerSeq) * TT;
  const _Float16* Xh = (const _Float16*)Xv + (size_t)nb * (2 * (size_t)T2) * 8;

  if constexpr (!IN16) {
    const float* X = (const float*)Xv;
    const float2* Xrow = (const float2*)(X + (size_t)nb * 8 * (2 * (size_t)T2));
    for (int jj = threadIdx.x; jj < TIN2; jj += 512) {
      int j = t0 - 4 + jj;
      j = j < 0 ? 0 : (j > T2 - 1 ? T2 - 1 : j);
      unsigned int u0[4], u1[4];
#pragma unroll
      for (int cp = 0; cp < 4; ++cp) {
        float2 a = Xrow[(size_t)(2 * cp) * T2 + j];
        float2 b = Xrow[(size_t)(2 * cp + 1) * T2 + j];
        u0[cp] = pku(a.x, b.x);                      // side0 = odd
        u1[cp] = pku(a.y, b.y);                      // side1 = even
      }
      *(uint4*)&inS[0][jj][0] = make_uint4(u0[0], u0[1], u0[2], u0[3]);
      *(uint4*)&inS[1][jj][0] = make_uint4(u1[0], u1[1], u1[2], u1[3]);
    }
    __syncthreads();
  }

  const int wid  = __builtin_amdgcn_readfirstlane((int)(threadIdx.x >> 6));
  const int lane = threadIdx.x & 63;
  const int side = wid >> 2, q = wid & 3;            // 2 sides x 4 quarters
  const int g = lane >> 4, col = lane & 15;
  // A-phase spans: q0 tiles 0-4, q1 5-8, q2 9-12, q3 13-16 (17 tiles).
  const int tstart = (q == 0) ? 0 : (1 + 4 * q);     // 0,5,9,13
  const int tcnt   = (q == 0) ? 5 : 4;
  const int rp = ((lane >> 4) & 1) * 2 + (lane >> 5);   // row-pair after lane_spread

  const int pa = lvl * 4 + (side ? 3 : 1);
  const int pb = lvl * 4 + (side ? 2 : 0);
  const f16x8 a1w0 = *(const f16x8*)&g_w1A[pa][0][lane][0];
  const f16x8 a1w1 = *(const f16x8*)&g_w1A[pa][1][lane][0];
  const f16x8 a2w0 = *(const f16x8*)&g_w2A[pa][0][lane][0];
  const f16x8 a2w1 = *(const f16x8*)&g_w2A[pa][1][lane][0];
  const f16x8 a2w2 = *(const f16x8*)&g_w2A[pa][2][lane][0];
  const f16x8 b1w0 = *(const f16x8*)&g_w1A[pb][0][lane][0];
  const f16x8 b1w1 = *(const f16x8*)&g_w1A[pb][1][lane][0];
  const f16x8 b2w0 = *(const f16x8*)&g_w2A[pb][0][lane][0];
  const f16x8 b2w1 = *(const f16x8*)&g_w2A[pb][1][lane][0];
  const f16x8 b2w2 = *(const f16x8*)&g_w2A[pb][2][lane][0];
  const f32x4 zero = {0.f, 0.f, 0.f, 0.f};

  // ---- A1: hidA rows (pos -3..TT+2); one swizzled b128 write/lane/tile ----
#pragma unroll
  for (int nt = 0; nt < 5; ++nt) {
    if (nt >= tcnt) break;
    const int row = tstart * 16 + nt * 16 + col;
    f16x8 bf;
    if constexpr (IN16) {
      int p = t0 - 4 + row + g;                      // clamp in side-position space
      p = p < 0 ? 0 : (p > T2 - 1 ? T2 - 1 : p);
      bf = *(const f16x8*)&Xh[(size_t)(2 * p + side) * 8];
    } else {
      const int rr = (row + g > TIN2 - 1) ? (TIN2 - 1) : (row + g);
      bf = *(const f16x8*)&inS[side][rr][0];
    }
    f32x4 d0 = __builtin_amdgcn_mfma_f32_16x16x32_f16(a1w0, bf, zero, 0, 0, 0);
    f32x4 d1 = __builtin_amdgcn_mfma_f32_16x16x32_f16(a1w1, bf, zero, 0, 0, 0);
    if (row < NHA) {
      *(uint4*)HID_PTR(hidS, side, row, g) = make_uint4(
          lky(pku(d0[0], d0[1])), lky(pku(d0[2], d0[3])),
          lky(pku(d1[0], d1[1])), lky(pku(d1[2], d1[3])));
    }
  }
  __syncthreads();

  // ---- A2: Es/Os rows (pos -2..TT+1), epilogue spread over all 64 lanes ----
#pragma unroll
  for (int nt = 0; nt < 5; ++nt) {
    if (nt >= tcnt) break;
    const int row = tstart * 16 + nt * 16 + col;
    f32x4 acc = zero;
    acc = __builtin_amdgcn_mfma_f32_16x16x32_f16(a2w0, *(const f16x8*)HID_PTR(hidS, side, row,     g), acc, 0, 0, 0);
    acc = __builtin_amdgcn_mfma_f32_16x16x32_f16(a2w1, *(const f16x8*)HID_PTR(hidS, side, row + 1, g), acc, 0, 0, 0);
    acc = __builtin_amdgcn_mfma_f32_16x16x32_f16(a2w2, *(const f16x8*)HID_PTR(hidS, side, row + 2, g), acc, 0, 0, 0);
    if (row < NEO) {
      const float va = lane_spread(acc[0], acc[2], lane);
      const float vb = lane_spread(acc[1], acc[3], lane);
      h2 mpk;
      if constexpr (IN16) {
        int pm = t0 + row - 2;
        pm = pm < 0 ? 0 : (pm > T2 - 1 ? T2 - 1 : pm);
        mpk = *(const h2*)&Xh[(size_t)(2 * pm + (side ^ 1)) * 8 + 2 * rp];
      } else {
        mpk = *(const h2*)&inS[side ^ 1][row + 2][2 * rp];
      }
      const float v0 = (float)mpk[0] * __expf(fast_tanh(va));
      const float v1 = (float)mpk[1] * __expf(fast_tanh(vb));
      *(unsigned int*)&esS[side][row][2 * rp] = pku(v0, v1);
    }
  }
  __syncthreads();

  // ---- B1: hidB rows (pos -1..TT), conv input = other side's Es/Os ----
  const int srcB = side ^ 1;
  const int eoLo = (t0 == 0) ? 2 : 0;                       // replicate-edge padding of Os/Es
  const int eoHi = (t0 + TT >= T2) ? (TT + 1) : (NEO - 1);
#pragma unroll
  for (int nt = 0; nt < 5; ++nt) {
    if (nt >= tcnt) break;
    const int row = tstart * 16 + nt * 16 + col;
    int rr = row + g;
    rr = rr < eoLo ? eoLo : (rr > eoHi ? eoHi : rr);
    const f16x8 bf = *(const f16x8*)&esS[srcB][rr][0];
    f32x4 d0 = __builtin_amdgcn_mfma_f32_16x16x32_f16(b1w0, bf, zero, 0, 0, 0);
    f32x4 d1 = __builtin_amdgcn_mfma_f32_16x16x32_f16(b1w1, bf, zero, 0, 0, 0);
    if (row < NHB) {
      *(uint4*)HID_PTR(hidS, side, row, g) = make_uint4(
          lky(pku(d0[0], d0[1])), lky(pku(d0[2], d0[3])),
          lky(pku(d1[0], d1[1])), lky(pku(d1[2], d1[3])));
    }
  }
  __syncthreads();

  // ---- B2: outputs (f16 pos-major), one coalesced 4B store per lane-iter ----
  const float sgn = side ? 1.f : -1.f;
  const int i = nb >> 7;          // B = 128
  const int b = nb & 127;
  const int outseq = 2 * i + side;
  _Float16* outbase = NEXT + ((size_t)outseq * 128 + b) * (size_t)T2 * 8;
#pragma unroll
  for (int nt = 0; nt < 4; ++nt) {
    const int row = q * 64 + nt * 16 + col;         // output pos, exact [0,256)
    f32x4 acc = zero;
    acc = __builtin_amdgcn_mfma_f32_16x16x32_f16(b2w0, *(const f16x8*)HID_PTR(hidS, side, row,     g), acc, 0, 0, 0);
    acc = __builtin_amdgcn_mfma_f32_16x16x32_f16(b2w1, *(const f16x8*)HID_PTR(hidS, side, row + 1, g), acc, 0, 0, 0);
    acc = __builtin_amdgcn_mfma_f32_16x16x32_f16(b2w2, *(const f16x8*)HID_PTR(hidS, side, row + 2, g), acc, 0, 0, 0);
    const float va = lane_spread(acc[0], acc[2], lane);
    const float vb = lane_spread(acc[1], acc[3], lane);
    const h2 base = *(const h2*)&esS[srcB][row + 2][2 * rp];
    const int tg = t0 + row;
    *(unsigned int*)&outbase[(size_t)tg * 8 + 2 * rp] =
        pku((float)base[0] + sgn * fast_tanh(va), (float)base[1] + sgn * fast_tanh(vb));
  }
}

// FC1 split-K (dot2, f16 operands): F[row][8t+r] = P[rev3(r)][b][t][c] + x[row][8t+r]
// P is f16 pos-major: [seq8*128+b][t(1024)][c(8)]
__global__ __launch_bounds__(256) void fc1_fused(
    const _Float16* __restrict__ P, const float* __restrict__ x,
    const float* __restrict__ W, float* __restrict__ partial)
{
  const int rt = blockIdx.x & 31;   // row tile: 32 rows
  const int ch = blockIdx.x >> 5;   // 16 chunks of 512 s
  const int s0 = ch * 512;
  __shared__ unsigned int Fl[32][68];   // h2 pairs: 64 h2 = 128 s per sub-block
  __shared__ unsigned int Wl[64][68];
  const int hg = threadIdx.x & 15;
  const int rg = threadIdx.x >> 4;  // 0..15
  float acc[2][4] = {{0.f, 0.f, 0.f, 0.f}, {0.f, 0.f, 0.f, 0.f}};

  for (int sb = 0; sb < 512; sb += 128) {
    __syncthreads();
    for (int i = threadIdx.x; i < 32 * 32; i += 256) {
      const int r = i >> 5, s4 = i & 31;
      const int row = rt * 32 + r;
      const int b = row >> 3, c = row & 7;
      const int base = s0 + sb + 4 * s4;
      const int t = base >> 3, r0 = base & 7;       // r0 in {0,4}
      const float4 xv = *(const float4*)(x + (size_t)row * 8192 + base);
      _Float16 p[4];
#pragma unroll
      for (int j = 0; j < 4; ++j) {
        const int rr = r0 + j;
        const int rev = ((rr & 1) << 2) | (rr & 2) | ((rr >> 2) & 1);   // bitrev3
        p[j] = P[(((size_t)rev * 128 + b) * 1024 + t) * 8 + c];
      }
      const h2 f01 = pkh(xv.x, xv.y) + (h2){p[0], p[1]};
      const h2 f23 = pkh(xv.z, xv.w) + (h2){p[2], p[3]};
      *(uint2*)&Fl[r][s4 * 2] = make_uint2(__builtin_bit_cast(unsigned int, f01),
                                           __builtin_bit_cast(unsigned int, f23));
    }
    for (int i = threadIdx.x; i < 64 * 32; i += 256) {
      const int hh = i >> 5, s4 = i & 31;
      float4 v = make_float4(0.f, 0.f, 0.f, 0.f);
      if (hh < 50) v = ((const float4*)(W + (size_t)hh * 8192 + s0 + sb))[s4];
      *(uint2*)&Wl[hh][s4 * 2] = make_uint2(pku(v.x, v.y), pku(v.z, v.w));
    }
    __syncthreads();
    for (int q = 0; q < 16; ++q) {
      const uint4 fa = *(const uint4*)&Fl[rg * 2][q * 4];
      const uint4 fb = *(const uint4*)&Fl[rg * 2 + 1][q * 4];
#pragma unroll
      for (int j = 0; j < 4; ++j) {
        const uint4 w = *(const uint4*)&Wl[hg + 16 * j][q * 4];
#pragma unroll
        for (int e = 0; e < 4; ++e) {
          const h2 we = __builtin_bit_cast(h2, (&w.x)[e]);
          acc[0][j] = __builtin_amdgcn_fdot2(we, __builtin_bit_cast(h2, (&fa.x)[e]), acc[0][j], false);
          acc[1][j] = __builtin_amdgcn_fdot2(we, __builtin_bit_cast(h2, (&fb.x)[e]), acc[1][j], false);
        }
      }
    }
  }
#pragma unroll
  for (int rr = 0; rr < 2; ++rr)
#pragma unroll
    for (int j = 0; j < 4; ++j)
      partial[((size_t)ch * 1024 + rt * 32 + rg * 2 + rr) * 64 + hg + 16 * j] = acc[rr][j];
}

// reduce partials + bias + relu, then FC2 -> out[row][24]; 4 rows per block
__global__ __launch_bounds__(256) void fc_stage2(
    const float* __restrict__ partial, const float* __restrict__ fc1b,
    const float* __restrict__ fc2w, const float* __restrict__ fc2b,
    float* __restrict__ out)
{
  const int rr = threadIdx.x >> 6;            // row within block: 0..3
  const int row = blockIdx.x * 4 + rr;
  const int h = threadIdx.x & 63;             // 0..63
  __shared__ float hs[4][64];
  float v = 0.f;
  if (h < 50) {
    for (int ch = 0; ch < 16; ++ch)
      v += partial[((size_t)ch * 1024 + row) * 64 + h];
    v += fc1b[h];
    v = v > 0.f ? v : 0.f;
  }
  hs[rr][h] = v;
  __syncthreads();
  if (h < 24) {
    float a = fc2b[h];
    for (int j = 0; j < 50; ++j)
      a = fmaf(hs[rr][j], fc2w[h * 50 + j], a);
    out[(size_t)row * 24 + h] = a;
  }
}

extern "C" void kernel_launch(void* const* d_in, const int* in_sizes, int n_in,
                              void* d_out, int out_size, void* d_ws, size_t ws_size,
                              hipStream_t stream)
{
  const float* x    = (const float*)d_in[0];
  const float* w1a  = (const float*)d_in[1];  // (3,4,32,8,3)
  const float* w2a  = (const float*)d_in[2];  // (3,4,8,32,3)
  const float* fc1w = (const float*)d_in[3];  // (50,8192)
  const float* fc1b = (const float*)d_in[4];  // (50,)
  const float* fc2w = (const float*)d_in[5];  // (24,50)
  const float* fc2b = (const float*)d_in[6];  // (24,)
  float* out = (float*)d_out;

  _Float16* bufA = (_Float16*)d_ws;                       // 8.4M halves (16.8 MB)
  _Float16* bufB = bufA + (size_t)9 * 1024 * 1024;        // 8.4M halves
  float* partial = (float*)((char*)d_ws + (size_t)40 * 1024 * 1024);  // 4 MB

  pack_mfma<<<dim3(15), dim3(256), 0, stream>>>(w1a, w2a);

  // lvl0: x(f32 ch-major) -> bufA(f16 pos-major) ; lvl1: bufA -> bufB ; lvl2: bufB -> bufA
  level_fused<false><<<dim3(2048), dim3(512), 0, stream>>>(x,    bufA, 0, 4096, 16);
  level_fused<true ><<<dim3(2048), dim3(512), 0, stream>>>(bufA, bufB, 1, 2048, 8);
  level_fused<true ><<<dim3(2048), dim3(512), 0, stream>>>(bufB, bufA, 2, 1024, 4);

  fc1_fused<<<dim3(512), dim3(256), 0, stream>>>(bufA, x, fc1w, partial);
  fc_stage2<<<dim3(256), dim3(256), 0, stream>>>(partial, fc1b, fc2w, fc2b, out);
  (void)in_sizes; (void)n_in; (void)out_size; (void)ws_size;
}

// Round 20
// 108.678 us; speedup vs baseline: 1.1706x; 1.0938x over previous
//
#include <hip/hip_runtime.h>

#define TT   256        // output positions per side per block
#define TIN2 (TT + 8)   // staged X: pos -4 .. TT+3
#define NHA  (TT + 6)   // hidA rows: pos -3 .. TT+2
#define NEO  (TT + 4)   // Es/Os rows: pos -2 .. TT+1
#define NHB  (TT + 2)   // hidB rows: pos -1 .. TT

typedef _Float16 h2 __attribute__((ext_vector_type(2)));
typedef __fp16 fp16v2 __attribute__((ext_vector_type(2)));
typedef _Float16 f16x8 __attribute__((ext_vector_type(8)));
typedef float f32x4 __attribute__((ext_vector_type(4)));

// MFMA A-fragments of conv weights (device-global; rewritten every launch).
__device__ _Float16 g_w1A[12][2][64][8];  // conv1: [lvl*4+pair][Mtile][lane][j], k=kk*8+ic (kk=3 zero)
__device__ _Float16 g_w2A[12][3][64][8];  // conv2: [lvl*4+pair][tap][lane][j], hc PERMUTED (see pack), oc rows 8..15 zero

__device__ __forceinline__ h2 pkh(float a, float b) {
  fp16v2 r = __builtin_amdgcn_cvt_pkrtz(a, b);
  return __builtin_bit_cast(h2, r);
}
__device__ __forceinline__ unsigned int pku(float a, float b) {
  return __builtin_bit_cast(unsigned int, pkh(a, b));
}
__device__ __forceinline__ float fast_tanh(float x) {
  return 1.f - __fdividef(2.f, __expf(2.f * x) + 1.f);
}
// packed leaky: max(x, 0.01x) elementwise on 2 halves (v_pk_mul + v_pk_max)
__device__ __forceinline__ unsigned int lky(unsigned int u) {
  h2 v = __builtin_bit_cast(h2, u);
  h2 s = v * (h2){(_Float16)0.01f, (_Float16)0.01f};
  h2 m = __builtin_elementwise_max(v, s);
  return __builtin_bit_cast(unsigned int, m);
}
// lanes 0-31 keep a; lanes 32-63 receive b from (lane-32). Known-good
// __shfl_xor form (v_permlane32_swap failed in both operand orders, R15/R16).
__device__ __forceinline__ float lane_spread(float a_low, float b_low, int lane) {
  float s = __shfl_xor(b_low, 32);
  return (lane >= 32) ? s : a_low;
}
// swizzled 16B-group slot within a 64B hid row (bijective per row, same on R/W)
#define HID_PTR(hid, side, row, g) (&(hid)[side][row][(((g) ^ (((row) >> 1) & 3)) * 8)])

__global__ __launch_bounds__(256) void pack_mfma(
    const float* __restrict__ w1, const float* __restrict__ w2)
{
  int id = blockIdx.x * 256 + threadIdx.x;
  if (id >= 12 * 5 * 64) return;
  const int lane = id & 63;
  const int rest = id >> 6;
  const int slot = rest % 5;
  const int pr   = rest / 5;           // lvl*4+pair
  if (slot < 2) {                      // conv1 A-fragment, M-tile = slot
    const int oc = slot * 16 + (lane & 15);
    const int bb = lane >> 4;          // tap index; bb=3 -> zero pad
#pragma unroll
    for (int j = 0; j < 8; ++j) {
      float v = (bb < 3) ? w1[((size_t)pr * 32 + oc) * 24 + j * 3 + bb] : 0.f;
      g_w1A[pr][slot][lane][j] = (_Float16)v;
    }
  } else {                             // conv2 A-fragment, tap t; hc permuted to match
    const int t = slot - 2;            // hid LDS layout: offset 8*kk+j -> hc below
    const int oc = lane & 15;
    const int kk = lane >> 4;
#pragma unroll
    for (int j = 0; j < 8; ++j) {
      const int hc = (j < 4) ? (4 * kk + j) : (16 + 4 * kk + (j - 4));
      float v = (oc < 8) ? w2[((size_t)pr * 8 + oc) * 96 + hc * 3 + t] : 0.f;
      g_w2A[pr][t][lane][j] = (_Float16)v;
    }
  }
}

// Fused level, 512 threads = 8 waves = 2 sides x 4 quarters (R14/R19 structure).
// IN16 levels: A1 B-fragment and A2 multiplier read directly from global
// (pos-major f16, L2-hot); lvl0 keeps LDS staging for the f32 transpose.
template <bool IN16>
__global__ __launch_bounds__(512) void level_fused(
    const void* __restrict__ Xv, _Float16* __restrict__ NEXT,
    int lvl, int T2, int tilesPerSeq)
{
  constexpr int INROWS = IN16 ? 1 : TIN2;               // inS unused when IN16
  __shared__ __align__(16) _Float16 inS[2][INROWS][8];  // [side][pos+4][ch]
  __shared__ __align__(16) _Float16 hidS[2][NHA][32];   // 64B rows, swizzled 16B groups
  __shared__ __align__(16) _Float16 esS[2][NEO][8];     // Es/Os f16 (B conv input + base)

  const int blk = blockIdx.x;
  const int nb  = blk / tilesPerSeq;
  const int t0  = (blk - nb * tilesPerSeq) * TT;
  const _Float16* Xh = (const _Float16*)Xv + (size_t)nb * (2 * (size_t)T2) * 8;

  if constexpr (!IN16) {
    const float* X = (const float*)Xv;
    const float2* Xrow = (const float2*)(X + (size_t)nb * 8 * (2 * (size_t)T2));
    for (int jj = threadIdx.x; jj < TIN2; jj += 512) {
      int j = t0 - 4 + jj;
      j = j < 0 ? 0 : (j > T2 - 1 ? T2 - 1 : j);
      unsigned int u0[4], u1[4];
#pragma unroll
      for (int cp = 0; cp < 4; ++cp) {
        float2 a = Xrow[(size_t)(2 * cp) * T2 + j];
        float2 b = Xrow[(size_t)(2 * cp + 1) * T2 + j];
        u0[cp] = pku(a.x, b.x);                      // side0 = odd
        u1[cp] = pku(a.y, b.y);                      // side1 = even
      }
      *(uint4*)&inS[0][jj][0] = make_uint4(u0[0], u0[1], u0[2], u0[3]);
      *(uint4*)&inS[1][jj][0] = make_uint4(u1[0], u1[1], u1[2], u1[3]);
    }
    __syncthreads();
  }

  const int wid  = __builtin_amdgcn_readfirstlane((int)(threadIdx.x >> 6));
  const int lane = threadIdx.x & 63;
  const int side = wid >> 2, q = wid & 3;            // 2 sides x 4 quarters
  const int g = lane >> 4, col = lane & 15;
  // A-phase spans: q0 tiles 0-4, q1 5-8, q2 9-12, q3 13-16 (17 tiles).
  const int tstart = (q == 0) ? 0 : (1 + 4 * q);     // 0,5,9,13
  const int tcnt   = (q == 0) ? 5 : 4;
  const int rp = ((lane >> 4) & 1) * 2 + (lane >> 5);   // row-pair after lane_spread

  const int pa = lvl * 4 + (side ? 3 : 1);
  const int pb = lvl * 4 + (side ? 2 : 0);
  const f16x8 a1w0 = *(const f16x8*)&g_w1A[pa][0][lane][0];
  const f16x8 a1w1 = *(const f16x8*)&g_w1A[pa][1][lane][0];
  const f16x8 a2w0 = *(const f16x8*)&g_w2A[pa][0][lane][0];
  const f16x8 a2w1 = *(const f16x8*)&g_w2A[pa][1][lane][0];
  const f16x8 a2w2 = *(const f16x8*)&g_w2A[pa][2][lane][0];
  const f16x8 b1w0 = *(const f16x8*)&g_w1A[pb][0][lane][0];
  const f16x8 b1w1 = *(const f16x8*)&g_w1A[pb][1][lane][0];
  const f16x8 b2w0 = *(const f16x8*)&g_w2A[pb][0][lane][0];
  const f16x8 b2w1 = *(const f16x8*)&g_w2A[pb][1][lane][0];
  const f16x8 b2w2 = *(const f16x8*)&g_w2A[pb][2][lane][0];
  const f32x4 zero = {0.f, 0.f, 0.f, 0.f};

  // ---- A1: hidA rows (pos -3..TT+2); one swizzled b128 write/lane/tile ----
#pragma unroll
  for (int nt = 0; nt < 5; ++nt) {
    if (nt >= tcnt) break;
    const int row = tstart * 16 + nt * 16 + col;
    f16x8 bf;
    if constexpr (IN16) {
      int p = t0 - 4 + row + g;                      // clamp in side-position space
      p = p < 0 ? 0 : (p > T2 - 1 ? T2 - 1 : p);
      bf = *(const f16x8*)&Xh[(size_t)(2 * p + side) * 8];
    } else {
      const int rr = (row + g > TIN2 - 1) ? (TIN2 - 1) : (row + g);
      bf = *(const f16x8*)&inS[side][rr][0];
    }
    f32x4 d0 = __builtin_amdgcn_mfma_f32_16x16x32_f16(a1w0, bf, zero, 0, 0, 0);
    f32x4 d1 = __builtin_amdgcn_mfma_f32_16x16x32_f16(a1w1, bf, zero, 0, 0, 0);
    if (row < NHA) {
      *(uint4*)HID_PTR(hidS, side, row, g) = make_uint4(
          lky(pku(d0[0], d0[1])), lky(pku(d0[2], d0[3])),
          lky(pku(d1[0], d1[1])), lky(pku(d1[2], d1[3])));
    }
  }
  __syncthreads();

  // ---- A2: Es/Os rows (pos -2..TT+1), epilogue spread over all 64 lanes ----
#pragma unroll
  for (int nt = 0; nt < 5; ++nt) {
    if (nt >= tcnt) break;
    const int row = tstart * 16 + nt * 16 + col;
    f32x4 acc = zero;
    acc = __builtin_amdgcn_mfma_f32_16x16x32_f16(a2w0, *(const f16x8*)HID_PTR(hidS, side, row,     g), acc, 0, 0, 0);
    acc = __builtin_amdgcn_mfma_f32_16x16x32_f16(a2w1, *(const f16x8*)HID_PTR(hidS, side, row + 1, g), acc, 0, 0, 0);
    acc = __builtin_amdgcn_mfma_f32_16x16x32_f16(a2w2, *(const f16x8*)HID_PTR(hidS, side, row + 2, g), acc, 0, 0, 0);
    if (row < NEO) {
      const float va = lane_spread(acc[0], acc[2], lane);
      const float vb = lane_spread(acc[1], acc[3], lane);
      h2 mpk;
      if constexpr (IN16) {
        int pm = t0 + row - 2;
        pm = pm < 0 ? 0 : (pm > T2 - 1 ? T2 - 1 : pm);
        mpk = *(const h2*)&Xh[(size_t)(2 * pm + (side ^ 1)) * 8 + 2 * rp];
      } else {
        mpk = *(const h2*)&inS[side ^ 1][row + 2][2 * rp];
      }
      const float v0 = (float)mpk[0] * __expf(fast_tanh(va));
      const float v1 = (float)mpk[1] * __expf(fast_tanh(vb));
      *(unsigned int*)&esS[side][row][2 * rp] = pku(v0, v1);
    }
  }
  __syncthreads();

  // ---- B1: hidB rows (pos -1..TT), conv input = other side's Es/Os ----
  const int srcB = side ^ 1;
  const int eoLo = (t0 == 0) ? 2 : 0;                       // replicate-edge padding of Os/Es
  const int eoHi = (t0 + TT >= T2) ? (TT + 1) : (NEO - 1);
#pragma unroll
  for (int nt = 0; nt < 5; ++nt) {
    if (nt >= tcnt) break;
    const int row = tstart * 16 + nt * 16 + col;
    int rr = row + g;
    rr = rr < eoLo ? eoLo : (rr > eoHi ? eoHi : rr);
    const f16x8 bf = *(const f16x8*)&esS[srcB][rr][0];
    f32x4 d0 = __builtin_amdgcn_mfma_f32_16x16x32_f16(b1w0, bf, zero, 0, 0, 0);
    f32x4 d1 = __builtin_amdgcn_mfma_f32_16x16x32_f16(b1w1, bf, zero, 0, 0, 0);
    if (row < NHB) {
      *(uint4*)HID_PTR(hidS, side, row, g) = make_uint4(
          lky(pku(d0[0], d0[1])), lky(pku(d0[2], d0[3])),
          lky(pku(d1[0], d1[1])), lky(pku(d1[2], d1[3])));
    }
  }
  __syncthreads();

  // ---- B2: outputs (f16 pos-major), one coalesced 4B store per lane-iter ----
  const float sgn = side ? 1.f : -1.f;
  const int i = nb >> 7;          // B = 128
  const int b = nb & 127;
  const int outseq = 2 * i + side;
  _Float16* outbase = NEXT + ((size_t)outseq * 128 + b) * (size_t)T2 * 8;
#pragma unroll
  for (int nt = 0; nt < 4; ++nt) {
    const int row = q * 64 + nt * 16 + col;         // output pos, exact [0,256)
    f32x4 acc = zero;
    acc = __builtin_amdgcn_mfma_f32_16x16x32_f16(b2w0, *(const f16x8*)HID_PTR(hidS, side, row,     g), acc, 0, 0, 0);
    acc = __builtin_amdgcn_mfma_f32_16x16x32_f16(b2w1, *(const f16x8*)HID_PTR(hidS, side, row + 1, g), acc, 0, 0, 0);
    acc = __builtin_amdgcn_mfma_f32_16x16x32_f16(b2w2, *(const f16x8*)HID_PTR(hidS, side, row + 2, g), acc, 0, 0, 0);
    const float va = lane_spread(acc[0], acc[2], lane);
    const float vb = lane_spread(acc[1], acc[3], lane);
    const h2 base = *(const h2*)&esS[srcB][row + 2][2 * rp];
    const int tg = t0 + row;
    *(unsigned int*)&outbase[(size_t)tg * 8 + 2 * rp] =
        pku((float)base[0] + sgn * fast_tanh(va), (float)base[1] + sgn * fast_tanh(vb));
  }
}

// FC1 split-K via MFMA: partial[ch][row][h64] = sum_s F[row][s]*W[h][s], where
// F[row][8t+r] = P[rev3(r)][b][t][c] + x[row][8t+r] (P f16 pos-major).
// Block = 256 thr = 4 waves; wave w: M-tile mt=w&1 (16 rows), N-strip nh=(w>>1)*32.
// Fl/Wl rows padded to 72 uints (288B = 18-bank stride: bijective row->bank).
__global__ __launch_bounds__(256) void fc1_mfma(
    const _Float16* __restrict__ P, const float* __restrict__ x,
    const float* __restrict__ W, float* __restrict__ partial)
{
  const int rt = blockIdx.x & 31;   // row tile: 32 rows
  const int ch = blockIdx.x >> 5;   // 16 chunks of 512 s
  const int s0 = ch * 512;
  __shared__ unsigned int Fl[32][72];   // h2 pairs: 64 uints = 128 s per sub-block
  __shared__ unsigned int Wl[64][72];

  const int wid  = __builtin_amdgcn_readfirstlane((int)(threadIdx.x >> 6));
  const int lane = threadIdx.x & 63;
  const int mn = lane & 15, kg = lane >> 4;
  const int mt = wid & 1;
  const int nh = (wid >> 1) * 32;

  const f32x4 zero = {0.f, 0.f, 0.f, 0.f};
  f32x4 acc0 = zero, acc1 = zero;

  for (int sb = 0; sb < 512; sb += 128) {
    __syncthreads();
    for (int i = threadIdx.x; i < 32 * 32; i += 256) {
      const int r = i >> 5, s4 = i & 31;
      const int row = rt * 32 + r;
      const int b = row >> 3, c = row & 7;
      const int base = s0 + sb + 4 * s4;
      const int t = base >> 3, r0 = base & 7;       // r0 in {0,4}
      const float4 xv = *(const float4*)(x + (size_t)row * 8192 + base);
      _Float16 p[4];
#pragma unroll
      for (int j = 0; j < 4; ++j) {
        const int rr = r0 + j;
        const int rev = ((rr & 1) << 2) | (rr & 2) | ((rr >> 2) & 1);   // bitrev3
        p[j] = P[(((size_t)rev * 128 + b) * 1024 + t) * 8 + c];
      }
      const h2 f01 = pkh(xv.x, xv.y) + (h2){p[0], p[1]};
      const h2 f23 = pkh(xv.z, xv.w) + (h2){p[2], p[3]};
      *(uint2*)&Fl[r][s4 * 2] = make_uint2(__builtin_bit_cast(unsigned int, f01),
                                           __builtin_bit_cast(unsigned int, f23));
    }
    for (int i = threadIdx.x; i < 64 * 32; i += 256) {
      const int hh = i >> 5, s4 = i & 31;
      float4 v = make_float4(0.f, 0.f, 0.f, 0.f);
      if (hh < 50) v = ((const float4*)(W + (size_t)hh * 8192 + s0 + sb))[s4];
      *(uint2*)&Wl[hh][s4 * 2] = make_uint2(pku(v.x, v.y), pku(v.z, v.w));
    }
    __syncthreads();
    // 4 k-steps of 32 s; A from Fl rows (M), B from Wl rows (N); both hold
    // their own k-run of 8 h2-elements at uint offset 16k + 4*kg.
#pragma unroll
    for (int k = 0; k < 4; ++k) {
      const int ko = 16 * k + 4 * kg;
      const f16x8 af = *(const f16x8*)&Fl[mt * 16 + mn][ko];
      const f16x8 b0 = *(const f16x8*)&Wl[nh + mn][ko];
      const f16x8 b1 = *(const f16x8*)&Wl[nh + 16 + mn][ko];
      acc0 = __builtin_amdgcn_mfma_f32_16x16x32_f16(af, b0, acc0, 0, 0, 0);
      acc1 = __builtin_amdgcn_mfma_f32_16x16x32_f16(af, b1, acc1, 0, 0, 0);
    }
  }
  // D layout: m = mt*16 + 4*kg + r (A index), n = nh(+16) + mn (B index)
  const size_t obase = ((size_t)ch * 1024 + rt * 32 + mt * 16 + 4 * kg) * 64 + nh + mn;
#pragma unroll
  for (int r = 0; r < 4; ++r) {
    partial[obase + (size_t)r * 64]      = acc0[r];
    partial[obase + (size_t)r * 64 + 16] = acc1[r];
  }
}

// reduce partials + bias + relu, then FC2 -> out[row][24]; 4 rows per block
__global__ __launch_bounds__(256) void fc_stage2(
    const float* __restrict__ partial, const float* __restrict__ fc1b,
    const float* __restrict__ fc2w, const float* __restrict__ fc2b,
    float* __restrict__ out)
{
  const int rr = threadIdx.x >> 6;            // row within block: 0..3
  const int row = blockIdx.x * 4 + rr;
  const int h = threadIdx.x & 63;             // 0..63
  __shared__ float hs[4][64];
  float v = 0.f;
  if (h < 50) {
    for (int ch = 0; ch < 16; ++ch)
      v += partial[((size_t)ch * 1024 + row) * 64 + h];
    v += fc1b[h];
    v = v > 0.f ? v : 0.f;
  }
  hs[rr][h] = v;
  __syncthreads();
  if (h < 24) {
    float a = fc2b[h];
    for (int j = 0; j < 50; ++j)
      a = fmaf(hs[rr][j], fc2w[h * 50 + j], a);
    out[(size_t)row * 24 + h] = a;
  }
}

extern "C" void kernel_launch(void* const* d_in, const int* in_sizes, int n_in,
                              void* d_out, int out_size, void* d_ws, size_t ws_size,
                              hipStream_t stream)
{
  const float* x    = (const float*)d_in[0];
  const float* w1a  = (const float*)d_in[1];  // (3,4,32,8,3)
  const float* w2a  = (const float*)d_in[2];  // (3,4,8,32,3)
  const float* fc1w = (const float*)d_in[3];  // (50,8192)
  const float* fc1b = (const float*)d_in[4];  // (50,)
  const float* fc2w = (const float*)d_in[5];  // (24,50)
  const float* fc2b = (const float*)d_in[6];  // (24,)
  float* out = (float*)d_out;

  _Float16* bufA = (_Float16*)d_ws;                       // 8.4M halves (16.8 MB)
  _Float16* bufB = bufA + (size_t)9 * 1024 * 1024;        // 8.4M halves
  float* partial = (float*)((char*)d_ws + (size_t)40 * 1024 * 1024);  // 4 MB

  pack_mfma<<<dim3(15), dim3(256), 0, stream>>>(w1a, w2a);

  // lvl0: x(f32 ch-major) -> bufA(f16 pos-major) ; lvl1: bufA -> bufB ; lvl2: bufB -> bufA
  level_fused<false><<<dim3(2048), dim3(512), 0, stream>>>(x,    bufA, 0, 4096, 16);
  level_fused<true ><<<dim3(2048), dim3(512), 0, stream>>>(bufA, bufB, 1, 2048, 8);
  level_fused<true ><<<dim3(2048), dim3(512), 0, stream>>>(bufB, bufA, 2, 1024, 4);

  fc1_mfma<<<dim3(512), dim3(256), 0, stream>>>(bufA, x, fc1w, partial);
  fc_stage2<<<dim3(256), dim3(256), 0, stream>>>(partial, fc1b, fc2w, fc2b, out);
  (void)in_sizes; (void)n_in; (void)out_size; (void)ws_size;
}